// Round 1
// baseline (100.309 us; speedup 1.0000x reference)
//
#include <hip/hip_runtime.h>
#include <math.h>

// Problem constants (from setup_inputs): B=16, N=8192, K=128, M=N+K=8320.
#define BB 16
#define NN 8192
#define KK 128
#define MM (NN + KK)

// ---------------------------------------------------------------------------
// Phase 1: per-roi IoU vs all K gt boxes -> max_ov, argmax, fg flag.
// Also writes bbox_inside_weights / bbox_outside_weights (original roi order).
// ---------------------------------------------------------------------------
__global__ __launch_bounds__(256) void ptl_phase1(
    const float* __restrict__ all_rois,   // (B,N,5)
    const float* __restrict__ gt_boxes,   // (B,K,5)
    int* __restrict__ fg_flags,           // (B,M)
    int* __restrict__ gt_assign,          // (B,M)
    float* __restrict__ out_inside,       // (B,M,4)
    float* __restrict__ out_outside)      // (B,M,4)
{
    __shared__ float s_gt[KK * 5];
    __shared__ float s_area[KK];
    __shared__ int   s_zero[KK];

    const int b   = blockIdx.y;
    const int tid = threadIdx.x;

    for (int t = tid; t < KK * 5; t += 256)
        s_gt[t] = gt_boxes[(size_t)b * KK * 5 + t];
    __syncthreads();
    if (tid < KK) {
        float gx1 = s_gt[tid * 5 + 0], gy1 = s_gt[tid * 5 + 1];
        float gx2 = s_gt[tid * 5 + 2], gy2 = s_gt[tid * 5 + 3];
        float gw = gx2 - gx1 + 1.0f, gh = gy2 - gy1 + 1.0f;
        s_area[tid] = gw * gh;
        s_zero[tid] = (gw == 1.0f && gh == 1.0f) ? 1 : 0;
    }
    __syncthreads();

    const int i = blockIdx.x * 256 + tid;
    if (i >= MM) return;

    float x1, y1, x2, y2;
    if (i < NN) {
        const float* p = all_rois + ((size_t)b * NN + i) * 5;
        x1 = p[1]; y1 = p[2]; x2 = p[3]; y2 = p[4];
    } else {
        const float* p = gt_boxes + ((size_t)b * KK + (i - NN)) * 5;
        x1 = p[0]; y1 = p[1]; x2 = p[2]; y2 = p[3];
    }
    const float aw = x2 - x1 + 1.0f, ah = y2 - y1 + 1.0f;
    const float area_a = aw * ah;
    const bool an_zero = (aw == 1.0f && ah == 1.0f);

    float best = -1e30f;
    int besti = 0;
    for (int k = 0; k < KK; ++k) {
        float gx1 = s_gt[k * 5 + 0], gy1 = s_gt[k * 5 + 1];
        float gx2 = s_gt[k * 5 + 2], gy2 = s_gt[k * 5 + 3];
        float iw = fminf(x2, gx2) - fmaxf(x1, gx1) + 1.0f;
        float ih = fminf(y2, gy2) - fmaxf(y1, gy1) + 1.0f;
        iw = fmaxf(iw, 0.0f);
        ih = fmaxf(ih, 0.0f);
        float inter = iw * ih;
        float ov = inter / (area_a + s_area[k] - inter);
        ov = s_zero[k] ? 0.0f : ov;          // zero-area gt -> 0
        if (ov > best) { best = ov; besti = k; }  // strict > == first-max (jnp.argmax)
    }
    if (an_zero) { best = -1.0f; besti = 0; }    // zero-area anchor -> all -1

    const bool fg = (best >= 0.5f);
    const size_t idx = (size_t)b * MM + i;
    fg_flags[idx]  = fg ? 1 : 0;
    gt_assign[idx] = besti;

    // focal inside/outside weights, ORIGINAL roi order
    const float om = 1.0f - best;
    const float w  = fg ? om * om : 0.0f;     // exactly 0 for IoU==1.0 (appended gt)
    const float ow = (w > 0.0f) ? 1.0f : 0.0f;
    float4* ip = (float4*)(out_inside + idx * 4);
    float4* op = (float4*)(out_outside + idx * 4);
    *ip = make_float4(w, w, w, w);
    *op = make_float4(ow, ow, ow, ow);
}

// ---------------------------------------------------------------------------
// Phase 2: per-batch stable partition (fg first, then bg, both in original
// order) via chunked ballot-scan; scatter rois_batch, labels_batch,
// bbox_targets.
// ---------------------------------------------------------------------------
__global__ __launch_bounds__(1024) void ptl_phase2(
    const float* __restrict__ all_rois,   // (B,N,5)
    const float* __restrict__ gt_boxes,   // (B,K,5)
    const int* __restrict__ fg_flags,     // (B,M)
    const int* __restrict__ gt_assign,    // (B,M)
    float* __restrict__ out_rois,         // (B,M,5)
    float* __restrict__ out_labels,       // (B,M)
    float* __restrict__ out_targets)      // (B,M,4)
{
    const int b    = blockIdx.x;
    const int tid  = threadIdx.x;
    const int lane = tid & 63;
    const int wave = tid >> 6;            // 0..15

    __shared__ float s_gt[KK * 5];
    __shared__ int   s_wavesum[16];
    __shared__ int   s_total;

    for (int t = tid; t < KK * 5; t += 1024)
        s_gt[t] = gt_boxes[(size_t)b * KK * 5 + t];

    // ---- pass 1: total fg count for this batch ----
    int local = 0;
    for (int i = tid; i < MM; i += 1024)
        local += fg_flags[(size_t)b * MM + i];
    for (int off = 32; off > 0; off >>= 1)
        local += __shfl_down(local, off, 64);
    if (lane == 0) s_wavesum[wave] = local;
    __syncthreads();
    if (tid == 0) {
        int t = 0;
        for (int wv = 0; wv < 16; ++wv) t += s_wavesum[wv];
        s_total = t;
    }
    __syncthreads();
    const int fgTotal = s_total;

    // ---- pass 2: chunked exclusive scan of fg flags + scatter outputs ----
    int carry = 0;   // fg count in chunks before this one (replicated)
    for (int base = 0; base < MM; base += 1024) {
        const int i = base + tid;
        int f = 0, a = 0;
        float x1 = 0, y1 = 0, x2 = 0, y2 = 0;
        if (i < MM) {
            f = fg_flags[(size_t)b * MM + i];
            a = gt_assign[(size_t)b * MM + i];
            if (i < NN) {
                const float* p = all_rois + ((size_t)b * NN + i) * 5;
                x1 = p[1]; y1 = p[2]; x2 = p[3]; y2 = p[4];
            } else {
                const float* p = gt_boxes + ((size_t)b * KK + (i - NN)) * 5;
                x1 = p[0]; y1 = p[1]; x2 = p[2]; y2 = p[3];
            }
        }
        const unsigned long long mask = __ballot(f);
        const int lanePrefix = __popcll(mask & ((1ull << lane) - 1ull));
        if (lane == 0) s_wavesum[wave] = __popcll(mask);
        __syncthreads();
        int waveExcl = 0, chunkTotal = 0;
        for (int wv = 0; wv < 16; ++wv) {
            int ws = s_wavesum[wv];
            chunkTotal += ws;
            if (wv < wave) waveExcl += ws;
        }
        const int excl = carry + waveExcl + lanePrefix;  // #fg strictly before i

        if (i < MM) {
            const int p = f ? excl : (fgTotal + (i - excl));
            float* rp = out_rois + ((size_t)b * MM + p) * 5;
            rp[0] = (float)b;
            rp[1] = x1; rp[2] = y1; rp[3] = x2; rp[4] = y2;

            float lbl = 0.0f, t0 = 0.0f, t1 = 0.0f, t2 = 0.0f, t3 = 0.0f;
            if (f) {
                lbl = s_gt[a * 5 + 4];
                if (lbl > 0.0f) {
                    const float gx1 = s_gt[a * 5 + 0], gy1 = s_gt[a * 5 + 1];
                    const float gx2 = s_gt[a * 5 + 2], gy2 = s_gt[a * 5 + 3];
                    const float ew = x2 - x1 + 1.0f, eh = y2 - y1 + 1.0f;
                    const float ecx = x1 + 0.5f * ew, ecy = y1 + 0.5f * eh;
                    const float gw = gx2 - gx1 + 1.0f, gh = gy2 - gy1 + 1.0f;
                    const float gcx = gx1 + 0.5f * gw, gcy = gy1 + 0.5f * gh;
                    t0 = ((gcx - ecx) / ew) / 0.1f;
                    t1 = ((gcy - ecy) / eh) / 0.1f;
                    t2 = logf(gw / ew) / 0.2f;
                    t3 = logf(gh / eh) / 0.2f;
                }
            }
            out_labels[(size_t)b * MM + p] = lbl;
            float* tp = out_targets + ((size_t)b * MM + p) * 4;
            tp[0] = t0; tp[1] = t1; tp[2] = t2; tp[3] = t3;
        }
        carry += chunkTotal;
        __syncthreads();   // s_wavesum reused next chunk
    }
}

extern "C" void kernel_launch(void* const* d_in, const int* in_sizes, int n_in,
                              void* d_out, int out_size, void* d_ws, size_t ws_size,
                              hipStream_t stream) {
    const float* all_rois = (const float*)d_in[0];   // (B,N,5)
    const float* gt_boxes = (const float*)d_in[1];   // (B,K,5)

    float* out = (float*)d_out;
    float* out_rois    = out;                              // (B,M,5)
    float* out_labels  = out_rois    + (size_t)BB * MM * 5;// (B,M)
    float* out_targets = out_labels  + (size_t)BB * MM;    // (B,M,4)
    float* out_inside  = out_targets + (size_t)BB * MM * 4;// (B,M,4)
    float* out_outside = out_inside  + (size_t)BB * MM * 4;// (B,M,4)

    int* fg_flags  = (int*)d_ws;                 // B*M ints
    int* gt_assign = fg_flags + (size_t)BB * MM; // B*M ints

    dim3 g1((MM + 255) / 256, BB);
    ptl_phase1<<<g1, 256, 0, stream>>>(all_rois, gt_boxes, fg_flags, gt_assign,
                                       out_inside, out_outside);
    ptl_phase2<<<BB, 1024, 0, stream>>>(all_rois, gt_boxes, fg_flags, gt_assign,
                                        out_rois, out_labels, out_targets);
}

// Round 2
// 83.300 us; speedup vs baseline: 1.2042x; 1.2042x over previous
//
#include <hip/hip_runtime.h>
#include <math.h>

// Problem constants (from setup_inputs): B=16, N=8192, K=128, M=N+K=8320.
#define BB 16
#define NN 8192
#define KK 128
#define MM (NN + KK)
#define NCHUNK ((MM + 255) / 256)   // 33

// ---------------------------------------------------------------------------
// Phase 1: per-roi IoU vs all K gt boxes -> fg flag, argmax, per-chunk fg
// counts. Also writes bbox_inside/outside_weights (original roi order).
//
// LDS holds one float4 per gt: {gx1, gy1, gx2+1, gy2+1}. Zero-area gt boxes
// (padding) get sentinel {+1e30,+1e30,-1e30,-1e30}: intersection clamps to 0
// and area_g overflows to +INF, so ov = 0/INF = 0 — exactly the reference's
// masked value. area_g is recomputed in VALU (3 ops) to keep the loop at a
// single ds_read_b128 per iteration (broadcast, conflict-free).
// Division stays exact IEEE f32 so max/argmax/threshold decisions are
// bit-identical to the NumPy reference (rcp-approx risks argmax tie flips).
// ---------------------------------------------------------------------------
__global__ __launch_bounds__(256) void ptl_phase1(
    const float* __restrict__ all_rois,   // (B,N,5)
    const float* __restrict__ gt_boxes,   // (B,K,5)
    int* __restrict__ fg_flags,           // (B,M)
    int* __restrict__ gt_assign,          // (B,M)
    int* __restrict__ chunk_counts,       // (B,NCHUNK)
    float* __restrict__ out_inside,       // (B,M,4)
    float* __restrict__ out_outside)      // (B,M,4)
{
    __shared__ float4 s_box[KK];
    __shared__ int    s_wcnt[4];

    const int b   = blockIdx.y;
    const int tid = threadIdx.x;

    if (tid < KK) {
        const float* g = gt_boxes + ((size_t)b * KK + tid) * 5;
        float gx1 = g[0], gy1 = g[1], gx2 = g[2], gy2 = g[3];
        float gw = gx2 - gx1 + 1.0f, gh = gy2 - gy1 + 1.0f;
        bool z = (gw == 1.0f) && (gh == 1.0f);
        s_box[tid] = z ? make_float4(1e30f, 1e30f, -1e30f, -1e30f)
                       : make_float4(gx1, gy1, gx2 + 1.0f, gy2 + 1.0f);
    }
    __syncthreads();

    const int i = blockIdx.x * 256 + tid;
    const bool valid = (i < MM);

    float x1 = 0.f, y1 = 0.f, x2 = 0.f, y2 = 0.f;
    if (valid) {
        if (i < NN) {
            const float* p = all_rois + ((size_t)b * NN + i) * 5;
            x1 = p[1]; y1 = p[2]; x2 = p[3]; y2 = p[4];
        } else {
            const float* p = gt_boxes + ((size_t)b * KK + (i - NN)) * 5;
            x1 = p[0]; y1 = p[1]; x2 = p[2]; y2 = p[3];
        }
    }
    const float X2p = x2 + 1.0f, Y2p = y2 + 1.0f;
    const float aw = X2p - x1, ah = Y2p - y1;
    const float area_a = aw * ah;

    float best = -1e30f;
    int besti = 0;
    #pragma unroll 4
    for (int k = 0; k < KK; ++k) {
        float4 g = s_box[k];
        float iw = fmaxf(fminf(X2p, g.z) - fmaxf(x1, g.x), 0.0f);
        float ih = fmaxf(fminf(Y2p, g.w) - fmaxf(y1, g.y), 0.0f);
        float inter = iw * ih;
        float area_g = (g.z - g.x) * (g.w - g.y);
        float ov = inter / (area_a + area_g - inter);   // exact IEEE divide
        if (ov > best) { best = ov; besti = k; }        // strict > == first-max
    }
    if (aw == 1.0f && ah == 1.0f) { best = -1.0f; besti = 0; }  // an_zero row

    const bool fg = valid && (best >= 0.5f);

    // per-chunk fg count (ballot reduce)
    unsigned long long m = __ballot(fg ? 1 : 0);
    if ((tid & 63) == 0) s_wcnt[tid >> 6] = __popcll(m);
    __syncthreads();
    if (tid == 0)
        chunk_counts[b * NCHUNK + blockIdx.x] =
            s_wcnt[0] + s_wcnt[1] + s_wcnt[2] + s_wcnt[3];

    if (!valid) return;
    const size_t idx = (size_t)b * MM + i;
    fg_flags[idx]  = fg ? 1 : 0;
    gt_assign[idx] = besti;

    const float om = 1.0f - best;
    const float w  = fg ? om * om : 0.0f;   // exactly 0 for IoU==1 (appended gt)
    const float ow = (w > 0.0f) ? 1.0f : 0.0f;
    ((float4*)out_inside)[idx]  = make_float4(w, w, w, w);
    ((float4*)out_outside)[idx] = make_float4(ow, ow, ow, ow);
}

// ---------------------------------------------------------------------------
// Phase 2: fully-parallel stable partition + scatter. Block (chunk,b) gets its
// fg prefix base by summing the 33 chunk counts (uniform loop, LDS-resident),
// ballot-scans fg within the block, scatters rois/labels/targets.
// ---------------------------------------------------------------------------
__global__ __launch_bounds__(256) void ptl_phase2(
    const float* __restrict__ all_rois,   // (B,N,5)
    const float* __restrict__ gt_boxes,   // (B,K,5)
    const int* __restrict__ fg_flags,     // (B,M)
    const int* __restrict__ gt_assign,    // (B,M)
    const int* __restrict__ chunk_counts, // (B,NCHUNK)
    float* __restrict__ out_rois,         // (B,M,5)
    float* __restrict__ out_labels,       // (B,M)
    float* __restrict__ out_targets)      // (B,M,4)
{
    __shared__ float s_gt[KK * 5];
    __shared__ int   s_cnt[NCHUNK];
    __shared__ int   s_w[4];

    const int b   = blockIdx.y;
    const int cx  = blockIdx.x;
    const int tid = threadIdx.x;

    for (int t = tid; t < KK * 5; t += 256)
        s_gt[t] = gt_boxes[(size_t)b * KK * 5 + t];
    if (tid < NCHUNK)
        s_cnt[tid] = chunk_counts[b * NCHUNK + tid];
    __syncthreads();

    int base = 0, total = 0;                    // uniform across block
    for (int c = 0; c < NCHUNK; ++c) {
        int v = s_cnt[c];
        total += v;
        if (c < cx) base += v;
    }

    const int i = cx * 256 + tid;
    const bool valid = (i < MM);
    int f = 0, a = 0;
    if (valid) {
        const size_t idx = (size_t)b * MM + i;
        f = fg_flags[idx];
        a = gt_assign[idx];
    }

    const int lane = tid & 63, wv = tid >> 6;
    unsigned long long m = __ballot(f);
    const int lp = __popcll(m & ((1ull << lane) - 1ull));
    if (lane == 0) s_w[wv] = __popcll(m);
    __syncthreads();
    int we = 0;
    for (int w2 = 0; w2 < wv; ++w2) we += s_w[w2];
    const int fgBefore = base + we + lp;        // #fg strictly before i in batch

    if (!valid) return;
    const int p = f ? fgBefore : (total + i - fgBefore);

    float x1, y1, x2, y2;
    if (i < NN) {
        const float* q = all_rois + ((size_t)b * NN + i) * 5;
        x1 = q[1]; y1 = q[2]; x2 = q[3]; y2 = q[4];
    } else {
        const float* q = gt_boxes + ((size_t)b * KK + (i - NN)) * 5;
        x1 = q[0]; y1 = q[1]; x2 = q[2]; y2 = q[3];
    }

    float* rp = out_rois + ((size_t)b * MM + p) * 5;
    rp[0] = (float)b;
    rp[1] = x1; rp[2] = y1; rp[3] = x2; rp[4] = y2;

    float lbl = 0.f, t0 = 0.f, t1 = 0.f, t2 = 0.f, t3 = 0.f;
    if (f) {
        lbl = s_gt[a * 5 + 4];
        if (lbl > 0.0f) {
            const float gx1 = s_gt[a * 5 + 0], gy1 = s_gt[a * 5 + 1];
            const float gx2 = s_gt[a * 5 + 2], gy2 = s_gt[a * 5 + 3];
            const float ew = x2 - x1 + 1.0f, eh = y2 - y1 + 1.0f;
            const float ecx = x1 + 0.5f * ew, ecy = y1 + 0.5f * eh;
            const float gw = gx2 - gx1 + 1.0f, gh = gy2 - gy1 + 1.0f;
            const float gcx = gx1 + 0.5f * gw, gcy = gy1 + 0.5f * gh;
            t0 = ((gcx - ecx) / ew) / 0.1f;
            t1 = ((gcy - ecy) / eh) / 0.1f;
            t2 = logf(gw / ew) / 0.2f;
            t3 = logf(gh / eh) / 0.2f;
        }
    }
    out_labels[(size_t)b * MM + p] = lbl;
    float* tp = out_targets + ((size_t)b * MM + p) * 4;
    tp[0] = t0; tp[1] = t1; tp[2] = t2; tp[3] = t3;
}

extern "C" void kernel_launch(void* const* d_in, const int* in_sizes, int n_in,
                              void* d_out, int out_size, void* d_ws, size_t ws_size,
                              hipStream_t stream) {
    const float* all_rois = (const float*)d_in[0];   // (B,N,5)
    const float* gt_boxes = (const float*)d_in[1];   // (B,K,5)

    float* out = (float*)d_out;
    float* out_rois    = out;                               // (B,M,5)
    float* out_labels  = out_rois    + (size_t)BB * MM * 5; // (B,M)
    float* out_targets = out_labels  + (size_t)BB * MM;     // (B,M,4)
    float* out_inside  = out_targets + (size_t)BB * MM * 4; // (B,M,4)
    float* out_outside = out_inside  + (size_t)BB * MM * 4; // (B,M,4)

    int* fg_flags     = (int*)d_ws;                        // B*M
    int* gt_assign    = fg_flags  + (size_t)BB * MM;       // B*M
    int* chunk_counts = gt_assign + (size_t)BB * MM;       // B*NCHUNK

    dim3 grid(NCHUNK, BB);
    ptl_phase1<<<grid, 256, 0, stream>>>(all_rois, gt_boxes, fg_flags, gt_assign,
                                         chunk_counts, out_inside, out_outside);
    ptl_phase2<<<grid, 256, 0, stream>>>(all_rois, gt_boxes, fg_flags, gt_assign,
                                         chunk_counts, out_rois, out_labels,
                                         out_targets);
}